// Round 10
// baseline (363.612 us; speedup 1.0000x reference)
//
#include <hip/hip_runtime.h>

#define NUM_USERS 100000
#define NUM_ITEMS 50000
#define NUM_OTHERS 20000
#define N_NODES 170000   // NUM_USERS + NUM_ITEMS + NUM_OTHERS
#define DIM 64
#define NNZ 5000000
#define BATCH 8192

#define BSHIFT 9
#define RPB (1 << BSHIFT)                       // 512 rows per bucket
#define NBUCK ((N_NODES + RPB - 1) / RPB)       // 333 buckets (ceil: 332.03 -> 333)
#define COLMASK 0x3FFFF                         // 18 bits for col (N_NODES < 2^18)
#define BCAPSHIFT 14
#define BCAP (1 << BCAPSHIFT)                   // 16384 slots/bucket (mean 15059, +10.8 sigma)
#define NBLK 1024                               // blocks for scatter pass
#define CHUNK ((NNZ + NBLK - 1) / NBLK)         // 4883 edges per block

typedef float f32x2 __attribute__((ext_vector_type(2)));

// fp32 -> bf16 round-to-nearest-even
static __device__ __forceinline__ unsigned f2bf(float f) {
    unsigned u = __float_as_uint(f);
    u = (u + 0x7fff + ((u >> 16) & 1)) >> 16;
    return u;
}
static __device__ __forceinline__ float bflo(unsigned u) {   // low ushort -> f32
    return __uint_as_float(u << 16);
}
static __device__ __forceinline__ float bfhi(unsigned u) {   // high ushort -> f32
    return __uint_as_float(u & 0xFFFF0000u);
}

// ---------------------------------------------------------------------------
// cur0 = concat(user_emb, item_emb, other_emb)  -> bf16
// ---------------------------------------------------------------------------
__global__ void build_cur0(const float* __restrict__ ue,
                           const float* __restrict__ ie,
                           const float* __restrict__ oe,
                           ushort4* __restrict__ cur) {
    const int total = N_NODES * (DIM / 4);
    for (int i = blockIdx.x * blockDim.x + threadIdx.x; i < total;
         i += gridDim.x * blockDim.x) {
        const int node = i >> 4;
        const int sub  = i & 15;
        const float* src;
        if (node < NUM_USERS)                  src = ue + (size_t)node * DIM;
        else if (node < NUM_USERS + NUM_ITEMS) src = ie + (size_t)(node - NUM_USERS) * DIM;
        else                                   src = oe + (size_t)(node - NUM_USERS - NUM_ITEMS) * DIM;
        const float4 f = reinterpret_cast<const float4*>(src)[sub];
        ushort4 o;
        o.x = (unsigned short)f2bf(f.x); o.y = (unsigned short)f2bf(f.y);
        o.z = (unsigned short)f2bf(f.z); o.w = (unsigned short)f2bf(f.w);
        cur[i] = o;
    }
}

// ---------------------------------------------------------------------------
// batch accumulators start as layer-0 embeddings (fp32)
// ---------------------------------------------------------------------------
__global__ void init_acc(const int* __restrict__ users,
                         const int* __restrict__ items,
                         const float* __restrict__ ue,
                         const float* __restrict__ ie,
                         float4* __restrict__ uacc,
                         float4* __restrict__ iacc) {
    const int total = BATCH * (DIM / 4);
    int i = blockIdx.x * blockDim.x + threadIdx.x;
    if (i >= total) return;
    const int b = i >> 4;
    const int sub = i & 15;
    uacc[i] = reinterpret_cast<const float4*>(ue + (size_t)users[b] * DIM)[sub];
    iacc[i] = reinterpret_cast<const float4*>(ie + (size_t)items[b] * DIM)[sub];
}

// ---------------------------------------------------------------------------
// Pass 1 (single scatter pass): per-block LDS bucket histogram of its chunk,
// reserve contiguous ranges in each bucket's FIXED-CAPACITY region (one
// global atomic per touched bucket), then append.
// Entry: .x = (local_row << 18) | col, .y = val bits.
// ---------------------------------------------------------------------------
__global__ __launch_bounds__(256) void bucket_scatter(const int* __restrict__ rows,
                                                      const int* __restrict__ cols,
                                                      const float* __restrict__ vals,
                                                      int* __restrict__ bucket_cnt,
                                                      int2* __restrict__ bkt) {
    __shared__ int h[NBUCK];
    __shared__ int base[NBUCK];
    for (int i = threadIdx.x; i < NBUCK; i += 256) h[i] = 0;
    __syncthreads();
    const int s = blockIdx.x * CHUNK;
    const int e = min(s + CHUNK, NNZ);
    for (int i = s + threadIdx.x; i < e; i += 256)
        atomicAdd(&h[rows[i] >> BSHIFT], 1);
    __syncthreads();
    for (int i = threadIdx.x; i < NBUCK; i += 256)
        base[i] = h[i] ? atomicAdd(&bucket_cnt[i], h[i]) : 0;
    __syncthreads();
    for (int i = threadIdx.x; i < NBUCK; i += 256) h[i] = 0;
    __syncthreads();
    for (int i = s + threadIdx.x; i < e; i += 256) {
        const int r  = rows[i];
        const int bk = r >> BSHIFT;
        const int lr = r & (RPB - 1);
        const int pos = base[bk] + atomicAdd(&h[bk], 1);
        bkt[((size_t)bk << BCAPSHIFT) + pos] = make_int2((lr << 18) | cols[i],
                                                         __float_as_int(vals[i]));
    }
}

// ---------------------------------------------------------------------------
// Pass 2: per-bucket counting sort -> final CSR inside the bucket's fixed
// region (no global prefix). Entry .x = col<<7 (byte offset into the bf16
// node matrix). rowinfo[row] = (abs_start << 8) | exact_len  (len < 256).
// 512 threads, 1 row per thread.
// ---------------------------------------------------------------------------
__global__ __launch_bounds__(512) void bucket_to_csr(const int* __restrict__ bucket_cnt,
                                                     const int2* __restrict__ bkt,
                                                     unsigned* __restrict__ rowinfo,
                                                     int2* __restrict__ packed) {
    __shared__ int cnt[RPB];
    __shared__ int rs[RPB];
    __shared__ int scan[RPB];
    const int k = blockIdx.x;
    const int rbase = k << BSHIFT;
    const int nvalid = min(RPB, N_NODES - rbase);
    const int n = bucket_cnt[k];
    const int2* __restrict__ src = bkt + ((size_t)k << BCAPSHIFT);
    int2* __restrict__ dst = packed + ((size_t)k << BCAPSHIFT);
    const int t = threadIdx.x;

    cnt[t] = 0;
    __syncthreads();
    for (int i = t; i < n; i += 512)
        atomicAdd(&cnt[src[i].x >> 18], 1);
    __syncthreads();

    // exclusive scan of 512 counts (Hillis-Steele, 1 elem/thread)
    const int v = cnt[t];
    int acc = v;
    scan[t] = v;
    __syncthreads();
    for (int off = 1; off < 512; off <<= 1) {
        const int add = (t >= off) ? scan[t - off] : 0;
        __syncthreads();
        acc += add;
        scan[t] = acc;
        __syncthreads();
    }
    const int excl = acc - v;
    rs[t] = excl;
    if (t < nvalid)
        rowinfo[rbase + t] = ((unsigned)((k << BCAPSHIFT) + excl) << 8) | (unsigned)v;
    __syncthreads();

    // scatter; atomicAdd on rs yields sequential positions within each row
    for (int i = t; i < n; i += 512) {
        const int2 pk = src[i];
        const int lr = pk.x >> 18;
        const int pos = atomicAdd(&rs[lr], 1);
        dst[pos] = make_int2((pk.x & COLMASK) << 7, pk.y);
    }
}

// ---------------------------------------------------------------------------
// SpMM gather core (frozen round-6 shape): 32 edge-slots per iteration,
// 8 lanes per edge (16B/lane); masked tail slots clamp to byte-offset 0
// (x[0]'s L1-resident line, ~free). Entry .x is the byte offset col*128.
// ---------------------------------------------------------------------------
static __device__ __forceinline__ void spmm_row_accum(
        const unsigned long long* __restrict__ packed,
        const unsigned short* __restrict__ x,
        int s, int e, int g, int d8b,
        f32x2& a0, f32x2& a1, f32x2& a2, f32x2& a3) {
    const char* xb = (const char*)x;
    for (int i = s; i < e; i += 32) {
        const int j0 = i + g;
        const int j1 = j0 + 8;
        const int j2 = j0 + 16;
        const int j3 = j0 + 24;
        const unsigned long long p0 = __builtin_nontemporal_load(packed + j0);
        const unsigned long long p1 = __builtin_nontemporal_load(packed + j1);
        const unsigned long long p2 = __builtin_nontemporal_load(packed + j2);
        const unsigned long long p3 = __builtin_nontemporal_load(packed + j3);
        const unsigned c0 = ((j0 < e) ? (unsigned)(p0 & 0xFFFFFFFFu) : 0u) + d8b;
        const unsigned c1 = ((j1 < e) ? (unsigned)(p1 & 0xFFFFFFFFu) : 0u) + d8b;
        const unsigned c2 = ((j2 < e) ? (unsigned)(p2 & 0xFFFFFFFFu) : 0u) + d8b;
        const unsigned c3 = ((j3 < e) ? (unsigned)(p3 & 0xFFFFFFFFu) : 0u) + d8b;
        const float v0 = (j0 < e) ? __uint_as_float((unsigned)(p0 >> 32)) : 0.f;
        const float v1 = (j1 < e) ? __uint_as_float((unsigned)(p1 >> 32)) : 0.f;
        const float v2 = (j2 < e) ? __uint_as_float((unsigned)(p2 >> 32)) : 0.f;
        const float v3 = (j3 < e) ? __uint_as_float((unsigned)(p3 >> 32)) : 0.f;
        const uint4 x0 = *reinterpret_cast<const uint4*>(xb + c0);
        const uint4 x1 = *reinterpret_cast<const uint4*>(xb + c1);
        const uint4 x2 = *reinterpret_cast<const uint4*>(xb + c2);
        const uint4 x3 = *reinterpret_cast<const uint4*>(xb + c3);
        const f32x2 w0 = {v0, v0}, w1 = {v1, v1}, w2 = {v2, v2}, w3 = {v3, v3};
        a0 += w0 * (f32x2){bflo(x0.x), bfhi(x0.x)};
        a1 += w0 * (f32x2){bflo(x0.y), bfhi(x0.y)};
        a2 += w0 * (f32x2){bflo(x0.z), bfhi(x0.z)};
        a3 += w0 * (f32x2){bflo(x0.w), bfhi(x0.w)};
        a0 += w1 * (f32x2){bflo(x1.x), bfhi(x1.x)};
        a1 += w1 * (f32x2){bflo(x1.y), bfhi(x1.y)};
        a2 += w1 * (f32x2){bflo(x1.z), bfhi(x1.z)};
        a3 += w1 * (f32x2){bflo(x1.w), bfhi(x1.w)};
        a0 += w2 * (f32x2){bflo(x2.x), bfhi(x2.x)};
        a1 += w2 * (f32x2){bflo(x2.y), bfhi(x2.y)};
        a2 += w2 * (f32x2){bflo(x2.z), bfhi(x2.z)};
        a3 += w2 * (f32x2){bflo(x2.w), bfhi(x2.w)};
        a0 += w3 * (f32x2){bflo(x3.x), bfhi(x3.x)};
        a1 += w3 * (f32x2){bflo(x3.y), bfhi(x3.y)};
        a2 += w3 * (f32x2){bflo(x3.z), bfhi(x3.z)};
        a3 += w3 * (f32x2){bflo(x3.w), bfhi(x3.w)};
    }
}

static __device__ __forceinline__ void butterfly8(f32x2& a0, f32x2& a1,
                                                  f32x2& a2, f32x2& a3) {
    #pragma unroll
    for (int off = 8; off < 64; off <<= 1) {
        a0.x += __shfl_xor(a0.x, off); a0.y += __shfl_xor(a0.y, off);
        a1.x += __shfl_xor(a1.x, off); a1.y += __shfl_xor(a1.y, off);
        a2.x += __shfl_xor(a2.x, off); a2.y += __shfl_xor(a2.y, off);
        a3.x += __shfl_xor(a3.x, off); a3.y += __shfl_xor(a3.y, off);
    }
}

// ---------------------------------------------------------------------------
// Full SpMM: one wave per row
// ---------------------------------------------------------------------------
__global__ __launch_bounds__(256) void spmm_csr8(const unsigned* __restrict__ rowinfo,
                                                 const unsigned long long* __restrict__ packed,
                                                 const unsigned short* __restrict__ x,
                                                 unsigned short* __restrict__ y) {
    const int row  = blockIdx.x * 4 + (threadIdx.x >> 6);
    const int lane = threadIdx.x & 63;
    if (row >= N_NODES) return;
    const unsigned info = rowinfo[row];
    const int s = (int)(info >> 8);
    const int e = s + (int)(info & 0xFFu);
    const int g   = lane >> 3;            // edge group 0..7
    const int d8b = (lane & 7) * 16;      // byte offset of this lane's 8 bf16 dims

    f32x2 a0 = {0, 0}, a1 = {0, 0}, a2 = {0, 0}, a3 = {0, 0};
    spmm_row_accum(packed, x, s, e, g, d8b, a0, a1, a2, a3);
    butterfly8(a0, a1, a2, a3);

    if (lane < 8) {
        uint4 o;
        o.x = f2bf(a0.x) | (f2bf(a0.y) << 16);
        o.y = f2bf(a1.x) | (f2bf(a1.y) << 16);
        o.z = f2bf(a2.x) | (f2bf(a2.y) << 16);
        o.w = f2bf(a3.x) | (f2bf(a3.y) << 16);
        *reinterpret_cast<uint4*>(y + (size_t)row * DIM + lane * 8) = o;
    }
}

// ---------------------------------------------------------------------------
// Layer-3: only batch rows, accumulate into fp32 uacc/iacc
// ---------------------------------------------------------------------------
__global__ __launch_bounds__(256) void spmm_batch_final8(const unsigned* __restrict__ rowinfo,
                                                         const unsigned long long* __restrict__ packed,
                                                         const unsigned short* __restrict__ x,
                                                         const int* __restrict__ users,
                                                         const int* __restrict__ items,
                                                         float* __restrict__ uacc,
                                                         float* __restrict__ iacc) {
    const int w    = blockIdx.x * 4 + (threadIdx.x >> 6);   // [0, 2*BATCH)
    const int lane = threadIdx.x & 63;
    if (w >= 2 * BATCH) return;
    const int b = w >> 1;
    const int isItem = w & 1;
    const int row = isItem ? (NUM_USERS + items[b]) : users[b];
    const unsigned info = rowinfo[row];
    const int s = (int)(info >> 8);
    const int e = s + (int)(info & 0xFFu);
    const int g   = lane >> 3;
    const int d8b = (lane & 7) * 16;

    f32x2 a0 = {0, 0}, a1 = {0, 0}, a2 = {0, 0}, a3 = {0, 0};
    spmm_row_accum(packed, x, s, e, g, d8b, a0, a1, a2, a3);
    butterfly8(a0, a1, a2, a3);

    if (lane < 8) {
        float* dst = (isItem ? iacc : uacc) + (size_t)b * DIM + lane * 8;
        float4 q0 = reinterpret_cast<float4*>(dst)[0];
        float4 q1 = reinterpret_cast<float4*>(dst)[1];
        q0.x += a0.x; q0.y += a0.y; q0.z += a1.x; q0.w += a1.y;
        q1.x += a2.x; q1.y += a2.y; q1.z += a3.x; q1.w += a3.y;
        reinterpret_cast<float4*>(dst)[0] = q0;
        reinterpret_cast<float4*>(dst)[1] = q1;
    }
}

// ---------------------------------------------------------------------------
// uacc/iacc += y (bf16) at the batch rows (layers 1 and 2)
// ---------------------------------------------------------------------------
__global__ void gather_add(const int* __restrict__ users,
                           const int* __restrict__ items,
                           const unsigned short* __restrict__ y,
                           float4* __restrict__ uacc,
                           float4* __restrict__ iacc) {
    const int total = BATCH * (DIM / 4);
    int i = blockIdx.x * blockDim.x + threadIdx.x;
    if (i >= total) return;
    const int b = i >> 4;
    const int sub = i & 15;
    const int un = users[b];
    const int in = NUM_USERS + items[b];
    float4 a = uacc[i];
    const ushort4 yu = *reinterpret_cast<const ushort4*>(y + (size_t)un * DIM + sub * 4);
    a.x += bflo(yu.x); a.y += bflo(yu.y); a.z += bflo(yu.z); a.w += bflo(yu.w);
    uacc[i] = a;
    float4 c = iacc[i];
    const ushort4 yi = *reinterpret_cast<const ushort4*>(y + (size_t)in * DIM + sub * 4);
    c.x += bflo(yi.x); c.y += bflo(yi.y); c.z += bflo(yi.z); c.w += bflo(yi.w);
    iacc[i] = c;
}

// ---------------------------------------------------------------------------
// gamma[b] = dot(uacc[b], iacc[b]) / 16
// ---------------------------------------------------------------------------
__global__ void dot_out(const float* __restrict__ uacc,
                        const float* __restrict__ iacc,
                        float* __restrict__ gamma) {
    const int b = blockIdx.x * (blockDim.x / 64) + (threadIdx.x / 64);
    const int lane = threadIdx.x & 63;
    if (b >= BATCH) return;
    float p = uacc[b * DIM + lane] * iacc[b * DIM + lane];
    #pragma unroll
    for (int off = 32; off > 0; off >>= 1) p += __shfl_down(p, off);
    if (lane == 0) gamma[b] = p * 0.0625f;
}

// ---------------------------------------------------------------------------
extern "C" void kernel_launch(void* const* d_in, const int* in_sizes, int n_in,
                              void* d_out, int out_size, void* d_ws, size_t ws_size,
                              hipStream_t stream) {
    const float* ue    = (const float*)d_in[0];
    const float* ie    = (const float*)d_in[1];
    const float* oe    = (const float*)d_in[2];
    const float* vals  = (const float*)d_in[3];
    const int*   rows  = (const int*)d_in[4];
    const int*   cols  = (const int*)d_in[5];
    const int*   users = (const int*)d_in[6];
    const int*   items = (const int*)d_in[7];
    float* out = (float*)d_out;

    // ---- workspace layout ----
    // bkt (43.7 MB) is dead after bucket_to_csr; cur (bf16, 21.8 MB) is
    // aliased on top (build_cur0 runs after pass 2).
    char* p = (char*)d_ws;
    int2* bkt = (int2*)p;                                      // 43.7 MB
    unsigned short* cur = (unsigned short*)p;                  // 21.76 MB (alias)
    p += ((size_t)NBUCK << BCAPSHIFT) * sizeof(int2);
    unsigned short* nxt = (unsigned short*)p;                  // 21.76 MB
    p += (size_t)N_NODES * DIM * sizeof(unsigned short);
    int2* packed = (int2*)p;                                   // 43.7 MB + tail pad
    p += (((size_t)NBUCK << BCAPSHIFT) + 64) * sizeof(int2);
    unsigned* rowinfo = (unsigned*)p;  p += (size_t)(N_NODES + 4) * sizeof(unsigned);
    int* bucket_cnt = (int*)p;  p += (size_t)(NBUCK + 4) * sizeof(int);
    float* uacc = (float*)p;  p += (size_t)BATCH * DIM * sizeof(float);
    float* iacc = (float*)p;  p += (size_t)BATCH * DIM * sizeof(float);

    // ---- CSR build: 2 passes, fixed-capacity buckets ----
    hipMemsetAsync(bucket_cnt, 0, (size_t)NBUCK * sizeof(int), stream);
    bucket_scatter<<<NBLK, 256, 0, stream>>>(rows, cols, vals, bucket_cnt, bkt);
    bucket_to_csr<<<NBUCK, 512, 0, stream>>>(bucket_cnt, bkt, rowinfo, packed);

    // ---- node matrix (aliased over dead bkt) + accumulator init ----
    build_cur0<<<2048, 256, 0, stream>>>(ue, ie, oe, (ushort4*)cur);
    init_acc<<<(BATCH * 16 + 255) / 256, 256, 0, stream>>>(users, items, ue, ie,
                                                           (float4*)uacc, (float4*)iacc);

    // ---- layers 1 and 2: full SpMM, accumulate batch rows ----
    for (int layer = 0; layer < 2; ++layer) {
        spmm_csr8<<<(N_NODES + 3) / 4, 256, 0, stream>>>(rowinfo,
                                                         (const unsigned long long*)packed,
                                                         cur, nxt);
        gather_add<<<(BATCH * 16 + 255) / 256, 256, 0, stream>>>(users, items, nxt,
                                                                 (float4*)uacc, (float4*)iacc);
        unsigned short* t = cur; cur = nxt; nxt = t;
    }

    // ---- layer 3: only the batch rows ----
    spmm_batch_final8<<<(2 * BATCH) / 4 + 1, 256, 0, stream>>>(rowinfo,
                                                               (const unsigned long long*)packed,
                                                               cur, users, items, uacc, iacc);

    // ---- output ----
    dot_out<<<BATCH / 4, 256, 0, stream>>>(uacc, iacc, out);
}

// Round 11
// 324.566 us; speedup vs baseline: 1.1203x; 1.1203x over previous
//
#include <hip/hip_runtime.h>

#define NUM_USERS 100000
#define NUM_ITEMS 50000
#define NUM_OTHERS 20000
#define N_NODES 170000   // NUM_USERS + NUM_ITEMS + NUM_OTHERS
#define DIM 64
#define NNZ 5000000
#define BATCH 8192

#define BSHIFT 10
#define RPB (1 << BSHIFT)                       // 1024 rows per bucket
#define NBUCK ((N_NODES + RPB - 1) / RPB)       // 167 buckets
#define COLMASK 0x3FFFF                         // 18 bits for col (N_NODES < 2^18)
#define BCAPSHIFT 15
#define BCAP (1 << BCAPSHIFT)                   // 32768 slots/bucket (mean 29940, +16 sigma)
#define NBLK 512                                // scatter chunks (range ~58 edges/bucket)
#define SBS 1024                                // scatter block size (fills wave slots)
#define CHUNK ((NNZ + NBLK - 1) / NBLK)         // 9766 edges per block

typedef float f32x2 __attribute__((ext_vector_type(2)));

// fp32 -> bf16 round-to-nearest-even
static __device__ __forceinline__ unsigned f2bf(float f) {
    unsigned u = __float_as_uint(f);
    u = (u + 0x7fff + ((u >> 16) & 1)) >> 16;
    return u;
}
static __device__ __forceinline__ float bflo(unsigned u) {   // low ushort -> f32
    return __uint_as_float(u << 16);
}
static __device__ __forceinline__ float bfhi(unsigned u) {   // high ushort -> f32
    return __uint_as_float(u & 0xFFFF0000u);
}

// ---------------------------------------------------------------------------
// cur0 = concat(user_emb, item_emb, other_emb)  -> bf16
// ---------------------------------------------------------------------------
__global__ void build_cur0(const float* __restrict__ ue,
                           const float* __restrict__ ie,
                           const float* __restrict__ oe,
                           ushort4* __restrict__ cur) {
    const int total = N_NODES * (DIM / 4);
    for (int i = blockIdx.x * blockDim.x + threadIdx.x; i < total;
         i += gridDim.x * blockDim.x) {
        const int node = i >> 4;
        const int sub  = i & 15;
        const float* src;
        if (node < NUM_USERS)                  src = ue + (size_t)node * DIM;
        else if (node < NUM_USERS + NUM_ITEMS) src = ie + (size_t)(node - NUM_USERS) * DIM;
        else                                   src = oe + (size_t)(node - NUM_USERS - NUM_ITEMS) * DIM;
        const float4 f = reinterpret_cast<const float4*>(src)[sub];
        ushort4 o;
        o.x = (unsigned short)f2bf(f.x); o.y = (unsigned short)f2bf(f.y);
        o.z = (unsigned short)f2bf(f.z); o.w = (unsigned short)f2bf(f.w);
        cur[i] = o;
    }
}

// ---------------------------------------------------------------------------
// batch accumulators start as layer-0 embeddings (fp32)
// ---------------------------------------------------------------------------
__global__ void init_acc(const int* __restrict__ users,
                         const int* __restrict__ items,
                         const float* __restrict__ ue,
                         const float* __restrict__ ie,
                         float4* __restrict__ uacc,
                         float4* __restrict__ iacc) {
    const int total = BATCH * (DIM / 4);
    int i = blockIdx.x * blockDim.x + threadIdx.x;
    if (i >= total) return;
    const int b = i >> 4;
    const int sub = i & 15;
    uacc[i] = reinterpret_cast<const float4*>(ue + (size_t)users[b] * DIM)[sub];
    iacc[i] = reinterpret_cast<const float4*>(ie + (size_t)items[b] * DIM)[sub];
}

// ---------------------------------------------------------------------------
// Pass 1 (single scatter pass): per-block LDS bucket histogram of its chunk,
// reserve contiguous ranges in each bucket's FIXED-CAPACITY region (one
// global atomic per touched bucket), then append. 1024-thread blocks fill
// the wave slots (round-10 lesson: more blocks shrinks ranges -> write amp;
// more waves per block keeps ranges at ~58 edges).
// Entry: .x = (local_row << 18) | col, .y = val bits.
// ---------------------------------------------------------------------------
__global__ __launch_bounds__(SBS) void bucket_scatter(const int* __restrict__ rows,
                                                      const int* __restrict__ cols,
                                                      const float* __restrict__ vals,
                                                      int* __restrict__ bucket_cnt,
                                                      int2* __restrict__ bkt) {
    __shared__ int h[NBUCK];
    __shared__ int base[NBUCK];
    for (int i = threadIdx.x; i < NBUCK; i += SBS) h[i] = 0;
    __syncthreads();
    const int s = blockIdx.x * CHUNK;
    const int e = min(s + CHUNK, NNZ);
    for (int i = s + threadIdx.x; i < e; i += SBS)
        atomicAdd(&h[rows[i] >> BSHIFT], 1);
    __syncthreads();
    for (int i = threadIdx.x; i < NBUCK; i += SBS)
        base[i] = h[i] ? atomicAdd(&bucket_cnt[i], h[i]) : 0;
    __syncthreads();
    for (int i = threadIdx.x; i < NBUCK; i += SBS) h[i] = 0;
    __syncthreads();
    for (int i = s + threadIdx.x; i < e; i += SBS) {
        const int r  = rows[i];
        const int bk = r >> BSHIFT;
        const int lr = r & (RPB - 1);
        const int pos = base[bk] + atomicAdd(&h[bk], 1);
        bkt[((size_t)bk << BCAPSHIFT) + pos] = make_int2((lr << 18) | cols[i],
                                                         __float_as_int(vals[i]));
    }
}

// ---------------------------------------------------------------------------
// Pass 2: per-bucket counting sort -> final CSR inside the bucket's fixed
// region (no global prefix). Entry .x = col<<7 (byte offset into the bf16
// node matrix). rowinfo[row] = (abs_start << 8) | exact_len  (len < 256).
// 1024 threads, 1 row per thread.
// ---------------------------------------------------------------------------
__global__ __launch_bounds__(1024) void bucket_to_csr(const int* __restrict__ bucket_cnt,
                                                      const int2* __restrict__ bkt,
                                                      unsigned* __restrict__ rowinfo,
                                                      int2* __restrict__ packed) {
    __shared__ int cnt[RPB];
    __shared__ int rs[RPB];
    __shared__ int scan[RPB];
    const int k = blockIdx.x;
    const int rbase = k << BSHIFT;
    const int nvalid = min(RPB, N_NODES - rbase);
    const int n = bucket_cnt[k];
    const int2* __restrict__ src = bkt + ((size_t)k << BCAPSHIFT);
    int2* __restrict__ dst = packed + ((size_t)k << BCAPSHIFT);
    const int t = threadIdx.x;

    cnt[t] = 0;
    __syncthreads();
    for (int i = t; i < n; i += 1024)
        atomicAdd(&cnt[src[i].x >> 18], 1);
    __syncthreads();

    // exclusive scan of 1024 counts (Hillis-Steele, 1 elem/thread)
    const int v = cnt[t];
    int acc = v;
    scan[t] = v;
    __syncthreads();
    for (int off = 1; off < 1024; off <<= 1) {
        const int add = (t >= off) ? scan[t - off] : 0;
        __syncthreads();
        acc += add;
        scan[t] = acc;
        __syncthreads();
    }
    const int excl = acc - v;
    rs[t] = excl;
    if (t < nvalid)
        rowinfo[rbase + t] = ((unsigned)((k << BCAPSHIFT) + excl) << 8) | (unsigned)v;
    __syncthreads();

    // scatter; atomicAdd on rs yields sequential positions within each row
    for (int i = t; i < n; i += 1024) {
        const int2 pk = src[i];
        const int lr = pk.x >> 18;
        const int pos = atomicAdd(&rs[lr], 1);
        dst[pos] = make_int2((pk.x & COLMASK) << 7, pk.y);
    }
}

// ---------------------------------------------------------------------------
// SpMM gather core (frozen round-6 shape): 32 edge-slots per iteration,
// 8 lanes per edge (16B/lane); masked tail slots clamp to byte-offset 0
// (x[0]'s L1-resident line, ~free). Entry .x is the byte offset col*128.
// ---------------------------------------------------------------------------
static __device__ __forceinline__ void spmm_row_accum(
        const unsigned long long* __restrict__ packed,
        const unsigned short* __restrict__ x,
        int s, int e, int g, int d8b,
        f32x2& a0, f32x2& a1, f32x2& a2, f32x2& a3) {
    const char* xb = (const char*)x;
    for (int i = s; i < e; i += 32) {
        const int j0 = i + g;
        const int j1 = j0 + 8;
        const int j2 = j0 + 16;
        const int j3 = j0 + 24;
        const unsigned long long p0 = __builtin_nontemporal_load(packed + j0);
        const unsigned long long p1 = __builtin_nontemporal_load(packed + j1);
        const unsigned long long p2 = __builtin_nontemporal_load(packed + j2);
        const unsigned long long p3 = __builtin_nontemporal_load(packed + j3);
        const unsigned c0 = ((j0 < e) ? (unsigned)(p0 & 0xFFFFFFFFu) : 0u) + d8b;
        const unsigned c1 = ((j1 < e) ? (unsigned)(p1 & 0xFFFFFFFFu) : 0u) + d8b;
        const unsigned c2 = ((j2 < e) ? (unsigned)(p2 & 0xFFFFFFFFu) : 0u) + d8b;
        const unsigned c3 = ((j3 < e) ? (unsigned)(p3 & 0xFFFFFFFFu) : 0u) + d8b;
        const float v0 = (j0 < e) ? __uint_as_float((unsigned)(p0 >> 32)) : 0.f;
        const float v1 = (j1 < e) ? __uint_as_float((unsigned)(p1 >> 32)) : 0.f;
        const float v2 = (j2 < e) ? __uint_as_float((unsigned)(p2 >> 32)) : 0.f;
        const float v3 = (j3 < e) ? __uint_as_float((unsigned)(p3 >> 32)) : 0.f;
        const uint4 x0 = *reinterpret_cast<const uint4*>(xb + c0);
        const uint4 x1 = *reinterpret_cast<const uint4*>(xb + c1);
        const uint4 x2 = *reinterpret_cast<const uint4*>(xb + c2);
        const uint4 x3 = *reinterpret_cast<const uint4*>(xb + c3);
        const f32x2 w0 = {v0, v0}, w1 = {v1, v1}, w2 = {v2, v2}, w3 = {v3, v3};
        a0 += w0 * (f32x2){bflo(x0.x), bfhi(x0.x)};
        a1 += w0 * (f32x2){bflo(x0.y), bfhi(x0.y)};
        a2 += w0 * (f32x2){bflo(x0.z), bfhi(x0.z)};
        a3 += w0 * (f32x2){bflo(x0.w), bfhi(x0.w)};
        a0 += w1 * (f32x2){bflo(x1.x), bfhi(x1.x)};
        a1 += w1 * (f32x2){bflo(x1.y), bfhi(x1.y)};
        a2 += w1 * (f32x2){bflo(x1.z), bfhi(x1.z)};
        a3 += w1 * (f32x2){bflo(x1.w), bfhi(x1.w)};
        a0 += w2 * (f32x2){bflo(x2.x), bfhi(x2.x)};
        a1 += w2 * (f32x2){bflo(x2.y), bfhi(x2.y)};
        a2 += w2 * (f32x2){bflo(x2.z), bfhi(x2.z)};
        a3 += w2 * (f32x2){bflo(x2.w), bfhi(x2.w)};
        a0 += w3 * (f32x2){bflo(x3.x), bfhi(x3.x)};
        a1 += w3 * (f32x2){bflo(x3.y), bfhi(x3.y)};
        a2 += w3 * (f32x2){bflo(x3.z), bfhi(x3.z)};
        a3 += w3 * (f32x2){bflo(x3.w), bfhi(x3.w)};
    }
}

static __device__ __forceinline__ void butterfly8(f32x2& a0, f32x2& a1,
                                                  f32x2& a2, f32x2& a3) {
    #pragma unroll
    for (int off = 8; off < 64; off <<= 1) {
        a0.x += __shfl_xor(a0.x, off); a0.y += __shfl_xor(a0.y, off);
        a1.x += __shfl_xor(a1.x, off); a1.y += __shfl_xor(a1.y, off);
        a2.x += __shfl_xor(a2.x, off); a2.y += __shfl_xor(a2.y, off);
        a3.x += __shfl_xor(a3.x, off); a3.y += __shfl_xor(a3.y, off);
    }
}

// ---------------------------------------------------------------------------
// Full SpMM: one wave per row
// ---------------------------------------------------------------------------
__global__ __launch_bounds__(256) void spmm_csr8(const unsigned* __restrict__ rowinfo,
                                                 const unsigned long long* __restrict__ packed,
                                                 const unsigned short* __restrict__ x,
                                                 unsigned short* __restrict__ y) {
    const int row  = blockIdx.x * 4 + (threadIdx.x >> 6);
    const int lane = threadIdx.x & 63;
    if (row >= N_NODES) return;
    const unsigned info = rowinfo[row];
    const int s = (int)(info >> 8);
    const int e = s + (int)(info & 0xFFu);
    const int g   = lane >> 3;            // edge group 0..7
    const int d8b = (lane & 7) * 16;      // byte offset of this lane's 8 bf16 dims

    f32x2 a0 = {0, 0}, a1 = {0, 0}, a2 = {0, 0}, a3 = {0, 0};
    spmm_row_accum(packed, x, s, e, g, d8b, a0, a1, a2, a3);
    butterfly8(a0, a1, a2, a3);

    if (lane < 8) {
        uint4 o;
        o.x = f2bf(a0.x) | (f2bf(a0.y) << 16);
        o.y = f2bf(a1.x) | (f2bf(a1.y) << 16);
        o.z = f2bf(a2.x) | (f2bf(a2.y) << 16);
        o.w = f2bf(a3.x) | (f2bf(a3.y) << 16);
        *reinterpret_cast<uint4*>(y + (size_t)row * DIM + lane * 8) = o;
    }
}

// ---------------------------------------------------------------------------
// Layer-3: only batch rows, accumulate into fp32 uacc/iacc
// ---------------------------------------------------------------------------
__global__ __launch_bounds__(256) void spmm_batch_final8(const unsigned* __restrict__ rowinfo,
                                                         const unsigned long long* __restrict__ packed,
                                                         const unsigned short* __restrict__ x,
                                                         const int* __restrict__ users,
                                                         const int* __restrict__ items,
                                                         float* __restrict__ uacc,
                                                         float* __restrict__ iacc) {
    const int w    = blockIdx.x * 4 + (threadIdx.x >> 6);   // [0, 2*BATCH)
    const int lane = threadIdx.x & 63;
    if (w >= 2 * BATCH) return;
    const int b = w >> 1;
    const int isItem = w & 1;
    const int row = isItem ? (NUM_USERS + items[b]) : users[b];
    const unsigned info = rowinfo[row];
    const int s = (int)(info >> 8);
    const int e = s + (int)(info & 0xFFu);
    const int g   = lane >> 3;
    const int d8b = (lane & 7) * 16;

    f32x2 a0 = {0, 0}, a1 = {0, 0}, a2 = {0, 0}, a3 = {0, 0};
    spmm_row_accum(packed, x, s, e, g, d8b, a0, a1, a2, a3);
    butterfly8(a0, a1, a2, a3);

    if (lane < 8) {
        float* dst = (isItem ? iacc : uacc) + (size_t)b * DIM + lane * 8;
        float4 q0 = reinterpret_cast<float4*>(dst)[0];
        float4 q1 = reinterpret_cast<float4*>(dst)[1];
        q0.x += a0.x; q0.y += a0.y; q0.z += a1.x; q0.w += a1.y;
        q1.x += a2.x; q1.y += a2.y; q1.z += a3.x; q1.w += a3.y;
        reinterpret_cast<float4*>(dst)[0] = q0;
        reinterpret_cast<float4*>(dst)[1] = q1;
    }
}

// ---------------------------------------------------------------------------
// uacc/iacc += y (bf16) at the batch rows (layers 1 and 2)
// ---------------------------------------------------------------------------
__global__ void gather_add(const int* __restrict__ users,
                           const int* __restrict__ items,
                           const unsigned short* __restrict__ y,
                           float4* __restrict__ uacc,
                           float4* __restrict__ iacc) {
    const int total = BATCH * (DIM / 4);
    int i = blockIdx.x * blockDim.x + threadIdx.x;
    if (i >= total) return;
    const int b = i >> 4;
    const int sub = i & 15;
    const int un = users[b];
    const int in = NUM_USERS + items[b];
    float4 a = uacc[i];
    const ushort4 yu = *reinterpret_cast<const ushort4*>(y + (size_t)un * DIM + sub * 4);
    a.x += bflo(yu.x); a.y += bflo(yu.y); a.z += bflo(yu.z); a.w += bflo(yu.w);
    uacc[i] = a;
    float4 c = iacc[i];
    const ushort4 yi = *reinterpret_cast<const ushort4*>(y + (size_t)in * DIM + sub * 4);
    c.x += bflo(yi.x); c.y += bflo(yi.y); c.z += bflo(yi.z); c.w += bflo(yi.w);
    iacc[i] = c;
}

// ---------------------------------------------------------------------------
// gamma[b] = dot(uacc[b], iacc[b]) / 16
// ---------------------------------------------------------------------------
__global__ void dot_out(const float* __restrict__ uacc,
                        const float* __restrict__ iacc,
                        float* __restrict__ gamma) {
    const int b = blockIdx.x * (blockDim.x / 64) + (threadIdx.x / 64);
    const int lane = threadIdx.x & 63;
    if (b >= BATCH) return;
    float p = uacc[b * DIM + lane] * iacc[b * DIM + lane];
    #pragma unroll
    for (int off = 32; off > 0; off >>= 1) p += __shfl_down(p, off);
    if (lane == 0) gamma[b] = p * 0.0625f;
}

// ---------------------------------------------------------------------------
extern "C" void kernel_launch(void* const* d_in, const int* in_sizes, int n_in,
                              void* d_out, int out_size, void* d_ws, size_t ws_size,
                              hipStream_t stream) {
    const float* ue    = (const float*)d_in[0];
    const float* ie    = (const float*)d_in[1];
    const float* oe    = (const float*)d_in[2];
    const float* vals  = (const float*)d_in[3];
    const int*   rows  = (const int*)d_in[4];
    const int*   cols  = (const int*)d_in[5];
    const int*   users = (const int*)d_in[6];
    const int*   items = (const int*)d_in[7];
    float* out = (float*)d_out;

    // ---- workspace layout ----
    // bkt (43.8 MB) is dead after bucket_to_csr; cur (bf16, 21.8 MB) is
    // aliased on top (build_cur0 runs after pass 2).
    char* p = (char*)d_ws;
    int2* bkt = (int2*)p;                                      // 43.8 MB
    unsigned short* cur = (unsigned short*)p;                  // 21.76 MB (alias)
    p += ((size_t)NBUCK << BCAPSHIFT) * sizeof(int2);
    unsigned short* nxt = (unsigned short*)p;                  // 21.76 MB
    p += (size_t)N_NODES * DIM * sizeof(unsigned short);
    int2* packed = (int2*)p;                                   // 43.8 MB + tail pad
    p += (((size_t)NBUCK << BCAPSHIFT) + 64) * sizeof(int2);
    unsigned* rowinfo = (unsigned*)p;  p += (size_t)(N_NODES + 4) * sizeof(unsigned);
    int* bucket_cnt = (int*)p;  p += (size_t)(NBUCK + 4) * sizeof(int);
    float* uacc = (float*)p;  p += (size_t)BATCH * DIM * sizeof(float);
    float* iacc = (float*)p;  p += (size_t)BATCH * DIM * sizeof(float);

    // ---- CSR build: 2 passes, fixed-capacity buckets ----
    hipMemsetAsync(bucket_cnt, 0, (size_t)NBUCK * sizeof(int), stream);
    bucket_scatter<<<NBLK, SBS, 0, stream>>>(rows, cols, vals, bucket_cnt, bkt);
    bucket_to_csr<<<NBUCK, 1024, 0, stream>>>(bucket_cnt, bkt, rowinfo, packed);

    // ---- node matrix (aliased over dead bkt) + accumulator init ----
    build_cur0<<<2048, 256, 0, stream>>>(ue, ie, oe, (ushort4*)cur);
    init_acc<<<(BATCH * 16 + 255) / 256, 256, 0, stream>>>(users, items, ue, ie,
                                                           (float4*)uacc, (float4*)iacc);

    // ---- layers 1 and 2: full SpMM, accumulate batch rows ----
    for (int layer = 0; layer < 2; ++layer) {
        spmm_csr8<<<(N_NODES + 3) / 4, 256, 0, stream>>>(rowinfo,
                                                         (const unsigned long long*)packed,
                                                         cur, nxt);
        gather_add<<<(BATCH * 16 + 255) / 256, 256, 0, stream>>>(users, items, nxt,
                                                                 (float4*)uacc, (float4*)iacc);
        unsigned short* t = cur; cur = nxt; nxt = t;
    }

    // ---- layer 3: only the batch rows ----
    spmm_batch_final8<<<(2 * BATCH) / 4 + 1, 256, 0, stream>>>(rowinfo,
                                                               (const unsigned long long*)packed,
                                                               cur, users, items, uacc, iacc);

    // ---- output ----
    dot_out<<<BATCH / 4, 256, 0, stream>>>(uacc, iacc, out);
}

// Round 12
// 312.074 us; speedup vs baseline: 1.1651x; 1.0400x over previous
//
#include <hip/hip_runtime.h>

#define NUM_USERS 100000
#define NUM_ITEMS 50000
#define NUM_OTHERS 20000
#define N_NODES 170000   // NUM_USERS + NUM_ITEMS + NUM_OTHERS
#define DIM 64
#define NNZ 5000000
#define BATCH 8192

#define BSHIFT 10
#define RPB (1 << BSHIFT)                       // 1024 rows per bucket
#define NBUCK ((N_NODES + RPB - 1) / RPB)       // 167 buckets
#define COLMASK 0x3FFFF                         // 18 bits for col (N_NODES < 2^18)
#define BCAPSHIFT 15
#define BCAP (1 << BCAPSHIFT)                   // 32768 slots/bucket (mean 29940, +16 sigma)
#define NBLK 512                                // scatter chunks (range ~58 edges/bucket)
#define SSBS 1024                               // scatter block threads
#define CHUNK ((NNZ + NBLK - 1) / NBLK)         // 9766 edges per block
#define SPMM_BLOCKS ((N_NODES + 3) / 4)         // 42500
#define GADD_BLOCKS ((BATCH * 16) / 256)        // 512

typedef float f32x2 __attribute__((ext_vector_type(2)));

// fp32 -> bf16 round-to-nearest-even
static __device__ __forceinline__ unsigned f2bf(float f) {
    unsigned u = __float_as_uint(f);
    u = (u + 0x7fff + ((u >> 16) & 1)) >> 16;
    return u;
}
static __device__ __forceinline__ float bflo(unsigned u) {   // low ushort -> f32
    return __uint_as_float(u << 16);
}
static __device__ __forceinline__ float bfhi(unsigned u) {   // high ushort -> f32
    return __uint_as_float(u & 0xFFFF0000u);
}

// ---------------------------------------------------------------------------
// Fused: cur0 = concat(embs)->bf16  (blocks 0..2047, grid-stride)
//        uacc/iacc = layer-0 batch embeddings (blocks 2048..2559)
// ---------------------------------------------------------------------------
__global__ void build_cur0_init(const float* __restrict__ ue,
                                const float* __restrict__ ie,
                                const float* __restrict__ oe,
                                ushort4* __restrict__ cur,
                                const int* __restrict__ users,
                                const int* __restrict__ items,
                                float4* __restrict__ uacc,
                                float4* __restrict__ iacc) {
    if (blockIdx.x < 2048) {
        const int total = N_NODES * (DIM / 4);
        for (int i = blockIdx.x * 256 + threadIdx.x; i < total; i += 2048 * 256) {
            const int node = i >> 4;
            const int sub  = i & 15;
            const float* src;
            if (node < NUM_USERS)                  src = ue + (size_t)node * DIM;
            else if (node < NUM_USERS + NUM_ITEMS) src = ie + (size_t)(node - NUM_USERS) * DIM;
            else                                   src = oe + (size_t)(node - NUM_USERS - NUM_ITEMS) * DIM;
            const float4 f = reinterpret_cast<const float4*>(src)[sub];
            ushort4 o;
            o.x = (unsigned short)f2bf(f.x); o.y = (unsigned short)f2bf(f.y);
            o.z = (unsigned short)f2bf(f.z); o.w = (unsigned short)f2bf(f.w);
            cur[i] = o;
        }
    } else {
        const int i = (blockIdx.x - 2048) * 256 + threadIdx.x;   // < 131072
        const int b = i >> 4;
        const int sub = i & 15;
        uacc[i] = reinterpret_cast<const float4*>(ue + (size_t)users[b] * DIM)[sub];
        iacc[i] = reinterpret_cast<const float4*>(ie + (size_t)items[b] * DIM)[sub];
    }
}

// ---------------------------------------------------------------------------
// Pass 1: LDS-staged bucket scatter. Per block: histogram its 9766-edge chunk,
// 256-wide scan -> local bucket layout, counting-sort the chunk INTO LDS
// (bucket-major), reserve global ranges (1 atomic per touched bucket), then
// write out COALESCED (consecutive staged indices -> consecutive global slots;
// bucket found by binary search over 167 local starts). Write amp ~1.05x vs
// 1.7x for direct scattered appends.
// ---------------------------------------------------------------------------
__global__ __launch_bounds__(SSBS) void bucket_scatter(const int* __restrict__ rows,
                                                       const int* __restrict__ cols,
                                                       const float* __restrict__ vals,
                                                       int* __restrict__ bucket_cnt,
                                                       int2* __restrict__ bkt) {
    __shared__ int2 stage[CHUNK];          // 78.1 KB
    __shared__ int h[NBUCK];
    __shared__ int lstart[NBUCK + 1];
    __shared__ int lcur[NBUCK];
    __shared__ int gbias[NBUCK];
    __shared__ int scanbuf[256];
    const int t = threadIdx.x;
    const int s = blockIdx.x * CHUNK;
    const int e = min(s + CHUNK, NNZ);
    const int n = e - s;

    for (int i = t; i < NBUCK; i += SSBS) h[i] = 0;
    __syncthreads();
    for (int i = s + t; i < e; i += SSBS)
        atomicAdd(&h[rows[i] >> BSHIFT], 1);
    __syncthreads();

    // 256-wide exclusive scan over the 167 bucket counts
    int v = 0;
    if (t < 256) { v = (t < NBUCK) ? h[t] : 0; scanbuf[t] = v; }
    __syncthreads();
    int acc = v;
    for (int off = 1; off < 256; off <<= 1) {
        int add = 0;
        if (t < 256 && t >= off) add = scanbuf[t - off];
        __syncthreads();
        if (t < 256) { acc += add; scanbuf[t] = acc; }
        __syncthreads();
    }
    if (t < NBUCK) {
        const int excl = acc - v;
        lstart[t] = excl;
        lcur[t]   = excl;
        const int gb = v ? atomicAdd(&bucket_cnt[t], v) : 0;
        gbias[t] = gb - excl;
    }
    if (t == 0) lstart[NBUCK] = n;
    __syncthreads();

    // counting-sort the chunk into LDS (bucket-major)
    for (int i = s + t; i < e; i += SSBS) {
        const int r  = rows[i];
        const int bk = r >> BSHIFT;
        const int pos = atomicAdd(&lcur[bk], 1);
        stage[pos] = make_int2(((r & (RPB - 1)) << 18) | cols[i],
                               __float_as_int(vals[i]));
    }
    __syncthreads();

    // coalesced write-out
    for (int i = t; i < n; i += SSBS) {
        int lo = 0, hi = NBUCK;
        while (hi - lo > 1) {
            const int mid = (lo + hi) >> 1;
            if (lstart[mid] <= i) lo = mid; else hi = mid;
        }
        bkt[((size_t)lo << BCAPSHIFT) + gbias[lo] + i] = stage[i];
    }
}

// ---------------------------------------------------------------------------
// Pass 2: per-bucket counting sort -> final CSR inside the bucket's fixed
// region. Entry .x = col<<7 (byte offset). rowinfo[row] = (start<<8) | len.
// ---------------------------------------------------------------------------
__global__ __launch_bounds__(1024) void bucket_to_csr(const int* __restrict__ bucket_cnt,
                                                      const int2* __restrict__ bkt,
                                                      unsigned* __restrict__ rowinfo,
                                                      int2* __restrict__ packed) {
    __shared__ int cnt[RPB];
    __shared__ int rs[RPB];
    __shared__ int scan[RPB];
    const int k = blockIdx.x;
    const int rbase = k << BSHIFT;
    const int nvalid = min(RPB, N_NODES - rbase);
    const int n = bucket_cnt[k];
    const int2* __restrict__ src = bkt + ((size_t)k << BCAPSHIFT);
    int2* __restrict__ dst = packed + ((size_t)k << BCAPSHIFT);
    const int t = threadIdx.x;

    cnt[t] = 0;
    __syncthreads();
    for (int i = t; i < n; i += 1024)
        atomicAdd(&cnt[src[i].x >> 18], 1);
    __syncthreads();

    const int v = cnt[t];
    int acc = v;
    scan[t] = v;
    __syncthreads();
    for (int off = 1; off < 1024; off <<= 1) {
        const int add = (t >= off) ? scan[t - off] : 0;
        __syncthreads();
        acc += add;
        scan[t] = acc;
        __syncthreads();
    }
    const int excl = acc - v;
    rs[t] = excl;
    if (t < nvalid)
        rowinfo[rbase + t] = ((unsigned)((k << BCAPSHIFT) + excl) << 8) | (unsigned)v;
    __syncthreads();

    for (int i = t; i < n; i += 1024) {
        const int2 pk = src[i];
        const int lr = pk.x >> 18;
        const int pos = atomicAdd(&rs[lr], 1);
        dst[pos] = make_int2((pk.x & COLMASK) << 7, pk.y);
    }
}

// ---------------------------------------------------------------------------
// SpMM gather core (frozen round-6 shape): 32 edge-slots/iter, 8 lanes/edge,
// 16B/lane; masked tail slots clamp to byte-offset 0 (L1-resident x[0] line).
// ---------------------------------------------------------------------------
static __device__ __forceinline__ void spmm_row_accum(
        const unsigned long long* __restrict__ packed,
        const unsigned short* __restrict__ x,
        int s, int e, int g, int d8b,
        f32x2& a0, f32x2& a1, f32x2& a2, f32x2& a3) {
    const char* xb = (const char*)x;
    for (int i = s; i < e; i += 32) {
        const int j0 = i + g;
        const int j1 = j0 + 8;
        const int j2 = j0 + 16;
        const int j3 = j0 + 24;
        const unsigned long long p0 = __builtin_nontemporal_load(packed + j0);
        const unsigned long long p1 = __builtin_nontemporal_load(packed + j1);
        const unsigned long long p2 = __builtin_nontemporal_load(packed + j2);
        const unsigned long long p3 = __builtin_nontemporal_load(packed + j3);
        const unsigned c0 = ((j0 < e) ? (unsigned)(p0 & 0xFFFFFFFFu) : 0u) + d8b;
        const unsigned c1 = ((j1 < e) ? (unsigned)(p1 & 0xFFFFFFFFu) : 0u) + d8b;
        const unsigned c2 = ((j2 < e) ? (unsigned)(p2 & 0xFFFFFFFFu) : 0u) + d8b;
        const unsigned c3 = ((j3 < e) ? (unsigned)(p3 & 0xFFFFFFFFu) : 0u) + d8b;
        const float v0 = (j0 < e) ? __uint_as_float((unsigned)(p0 >> 32)) : 0.f;
        const float v1 = (j1 < e) ? __uint_as_float((unsigned)(p1 >> 32)) : 0.f;
        const float v2 = (j2 < e) ? __uint_as_float((unsigned)(p2 >> 32)) : 0.f;
        const float v3 = (j3 < e) ? __uint_as_float((unsigned)(p3 >> 32)) : 0.f;
        const uint4 x0 = *reinterpret_cast<const uint4*>(xb + c0);
        const uint4 x1 = *reinterpret_cast<const uint4*>(xb + c1);
        const uint4 x2 = *reinterpret_cast<const uint4*>(xb + c2);
        const uint4 x3 = *reinterpret_cast<const uint4*>(xb + c3);
        const f32x2 w0 = {v0, v0}, w1 = {v1, v1}, w2 = {v2, v2}, w3 = {v3, v3};
        a0 += w0 * (f32x2){bflo(x0.x), bfhi(x0.x)};
        a1 += w0 * (f32x2){bflo(x0.y), bfhi(x0.y)};
        a2 += w0 * (f32x2){bflo(x0.z), bfhi(x0.z)};
        a3 += w0 * (f32x2){bflo(x0.w), bfhi(x0.w)};
        a0 += w1 * (f32x2){bflo(x1.x), bfhi(x1.x)};
        a1 += w1 * (f32x2){bflo(x1.y), bfhi(x1.y)};
        a2 += w1 * (f32x2){bflo(x1.z), bfhi(x1.z)};
        a3 += w1 * (f32x2){bflo(x1.w), bfhi(x1.w)};
        a0 += w2 * (f32x2){bflo(x2.x), bfhi(x2.x)};
        a1 += w2 * (f32x2){bflo(x2.y), bfhi(x2.y)};
        a2 += w2 * (f32x2){bflo(x2.z), bfhi(x2.z)};
        a3 += w2 * (f32x2){bflo(x2.w), bfhi(x2.w)};
        a0 += w3 * (f32x2){bflo(x3.x), bfhi(x3.x)};
        a1 += w3 * (f32x2){bflo(x3.y), bfhi(x3.y)};
        a2 += w3 * (f32x2){bflo(x3.z), bfhi(x3.z)};
        a3 += w3 * (f32x2){bflo(x3.w), bfhi(x3.w)};
    }
}

static __device__ __forceinline__ void butterfly8(f32x2& a0, f32x2& a1,
                                                  f32x2& a2, f32x2& a3) {
    #pragma unroll
    for (int off = 8; off < 64; off <<= 1) {
        a0.x += __shfl_xor(a0.x, off); a0.y += __shfl_xor(a0.y, off);
        a1.x += __shfl_xor(a1.x, off); a1.y += __shfl_xor(a1.y, off);
        a2.x += __shfl_xor(a2.x, off); a2.y += __shfl_xor(a2.y, off);
        a3.x += __shfl_xor(a3.x, off); a3.y += __shfl_xor(a3.y, off);
    }
}

// ---------------------------------------------------------------------------
// Full SpMM: one wave per row. Blocks >= SPMM_BLOCKS (only present on the
// layer-2 launch) perform the PREVIOUS layer's batch gather_add, reading this
// kernel's INPUT x — no write overlap with the spmm blocks (they write y).
// ---------------------------------------------------------------------------
__global__ __launch_bounds__(256) void spmm_csr8(const unsigned* __restrict__ rowinfo,
                                                 const unsigned long long* __restrict__ packed,
                                                 const unsigned short* __restrict__ x,
                                                 unsigned short* __restrict__ y,
                                                 const int* __restrict__ users,
                                                 const int* __restrict__ items,
                                                 float4* __restrict__ uacc4,
                                                 float4* __restrict__ iacc4) {
    if (blockIdx.x >= SPMM_BLOCKS) {
        // fused gather_add: uacc/iacc += x at batch rows (x = prev layer out)
        const int i = (blockIdx.x - SPMM_BLOCKS) * 256 + threadIdx.x;  // < 131072
        const int b = i >> 4;
        const int sub = i & 15;
        const int un = users[b];
        const int in = NUM_USERS + items[b];
        float4 a = uacc4[i];
        const ushort4 yu = *reinterpret_cast<const ushort4*>(x + (size_t)un * DIM + sub * 4);
        a.x += bflo(yu.x); a.y += bflo(yu.y); a.z += bflo(yu.z); a.w += bflo(yu.w);
        uacc4[i] = a;
        float4 c = iacc4[i];
        const ushort4 yi = *reinterpret_cast<const ushort4*>(x + (size_t)in * DIM + sub * 4);
        c.x += bflo(yi.x); c.y += bflo(yi.y); c.z += bflo(yi.z); c.w += bflo(yi.w);
        iacc4[i] = c;
        return;
    }
    const int row  = blockIdx.x * 4 + (threadIdx.x >> 6);
    const int lane = threadIdx.x & 63;
    if (row >= N_NODES) return;
    const unsigned info = rowinfo[row];
    const int s = (int)(info >> 8);
    const int e = s + (int)(info & 0xFFu);
    const int g   = lane >> 3;
    const int d8b = (lane & 7) * 16;

    f32x2 a0 = {0, 0}, a1 = {0, 0}, a2 = {0, 0}, a3 = {0, 0};
    spmm_row_accum(packed, x, s, e, g, d8b, a0, a1, a2, a3);
    butterfly8(a0, a1, a2, a3);

    if (lane < 8) {
        uint4 o;
        o.x = f2bf(a0.x) | (f2bf(a0.y) << 16);
        o.y = f2bf(a1.x) | (f2bf(a1.y) << 16);
        o.z = f2bf(a2.x) | (f2bf(a2.y) << 16);
        o.w = f2bf(a3.x) | (f2bf(a3.y) << 16);
        *reinterpret_cast<uint4*>(y + (size_t)row * DIM + lane * 8) = o;
    }
}

// ---------------------------------------------------------------------------
// Layer-3: only batch rows. Epilogue also folds in the layer-2 gather_add
// (dst += x[row] + layer3_row_sum) — one kernel instead of two, race-free
// because each (b, side) is owned by exactly one wave's lane<8 group.
// ---------------------------------------------------------------------------
__global__ __launch_bounds__(256) void spmm_batch_final8(const unsigned* __restrict__ rowinfo,
                                                         const unsigned long long* __restrict__ packed,
                                                         const unsigned short* __restrict__ x,
                                                         const int* __restrict__ users,
                                                         const int* __restrict__ items,
                                                         float* __restrict__ uacc,
                                                         float* __restrict__ iacc) {
    const int w    = blockIdx.x * 4 + (threadIdx.x >> 6);   // [0, 2*BATCH)
    const int lane = threadIdx.x & 63;
    if (w >= 2 * BATCH) return;
    const int b = w >> 1;
    const int isItem = w & 1;
    const int row = isItem ? (NUM_USERS + items[b]) : users[b];
    const unsigned info = rowinfo[row];
    const int s = (int)(info >> 8);
    const int e = s + (int)(info & 0xFFu);
    const int g   = lane >> 3;
    const int d8b = (lane & 7) * 16;

    f32x2 a0 = {0, 0}, a1 = {0, 0}, a2 = {0, 0}, a3 = {0, 0};
    spmm_row_accum(packed, x, s, e, g, d8b, a0, a1, a2, a3);
    butterfly8(a0, a1, a2, a3);

    if (lane < 8) {
        // own-row layer-2 value (the folded gather_add)
        const ushort4 xa = *reinterpret_cast<const ushort4*>(x + (size_t)row * DIM + lane * 8);
        const ushort4 xc = *reinterpret_cast<const ushort4*>(x + (size_t)row * DIM + lane * 8 + 4);
        float* dst = (isItem ? iacc : uacc) + (size_t)b * DIM + lane * 8;
        float4 q0 = reinterpret_cast<float4*>(dst)[0];
        float4 q1 = reinterpret_cast<float4*>(dst)[1];
        q0.x += a0.x + bflo(xa.x); q0.y += a0.y + bflo(xa.y);
        q0.z += a1.x + bflo(xa.z); q0.w += a1.y + bflo(xa.w);
        q1.x += a2.x + bflo(xc.x); q1.y += a2.y + bflo(xc.y);
        q1.z += a3.x + bflo(xc.z); q1.w += a3.y + bflo(xc.w);
        reinterpret_cast<float4*>(dst)[0] = q0;
        reinterpret_cast<float4*>(dst)[1] = q1;
    }
}

// ---------------------------------------------------------------------------
// gamma[b] = dot(uacc[b], iacc[b]) / 16
// ---------------------------------------------------------------------------
__global__ void dot_out(const float* __restrict__ uacc,
                        const float* __restrict__ iacc,
                        float* __restrict__ gamma) {
    const int b = blockIdx.x * (blockDim.x / 64) + (threadIdx.x / 64);
    const int lane = threadIdx.x & 63;
    if (b >= BATCH) return;
    float p = uacc[b * DIM + lane] * iacc[b * DIM + lane];
    #pragma unroll
    for (int off = 32; off > 0; off >>= 1) p += __shfl_down(p, off);
    if (lane == 0) gamma[b] = p * 0.0625f;
}

// ---------------------------------------------------------------------------
extern "C" void kernel_launch(void* const* d_in, const int* in_sizes, int n_in,
                              void* d_out, int out_size, void* d_ws, size_t ws_size,
                              hipStream_t stream) {
    const float* ue    = (const float*)d_in[0];
    const float* ie    = (const float*)d_in[1];
    const float* oe    = (const float*)d_in[2];
    const float* vals  = (const float*)d_in[3];
    const int*   rows  = (const int*)d_in[4];
    const int*   cols  = (const int*)d_in[5];
    const int*   users = (const int*)d_in[6];
    const int*   items = (const int*)d_in[7];
    float* out = (float*)d_out;

    // ---- workspace layout ----
    // bkt (43.8 MB) is dead after bucket_to_csr; cur (bf16, 21.8 MB) is
    // aliased on top (build_cur0_init runs after pass 2).
    char* p = (char*)d_ws;
    int2* bkt = (int2*)p;                                      // 43.8 MB
    unsigned short* cur = (unsigned short*)p;                  // 21.76 MB (alias)
    p += ((size_t)NBUCK << BCAPSHIFT) * sizeof(int2);
    unsigned short* nxt = (unsigned short*)p;                  // 21.76 MB
    p += (size_t)N_NODES * DIM * sizeof(unsigned short);
    int2* packed = (int2*)p;                                   // 43.8 MB + tail pad
    p += (((size_t)NBUCK << BCAPSHIFT) + 64) * sizeof(int2);
    unsigned* rowinfo = (unsigned*)p;  p += (size_t)(N_NODES + 4) * sizeof(unsigned);
    int* bucket_cnt = (int*)p;  p += (size_t)(NBUCK + 4) * sizeof(int);
    float* uacc = (float*)p;  p += (size_t)BATCH * DIM * sizeof(float);
    float* iacc = (float*)p;  p += (size_t)BATCH * DIM * sizeof(float);

    // ---- CSR build: 2 passes, fixed-capacity buckets ----
    hipMemsetAsync(bucket_cnt, 0, (size_t)NBUCK * sizeof(int), stream);
    bucket_scatter<<<NBLK, SSBS, 0, stream>>>(rows, cols, vals, bucket_cnt, bkt);
    bucket_to_csr<<<NBUCK, 1024, 0, stream>>>(bucket_cnt, bkt, rowinfo, packed);

    // ---- node matrix (aliased over dead bkt) + accumulator init (fused) ----
    build_cur0_init<<<2048 + GADD_BLOCKS, 256, 0, stream>>>(ue, ie, oe, (ushort4*)cur,
                                                            users, items,
                                                            (float4*)uacc, (float4*)iacc);

    // ---- layer 1: full SpMM (no fused gadd blocks) ----
    spmm_csr8<<<SPMM_BLOCKS, 256, 0, stream>>>(rowinfo,
                                               (const unsigned long long*)packed,
                                               cur, nxt, users, items,
                                               (float4*)uacc, (float4*)iacc);

    // ---- layer 2: full SpMM + fused layer-1 gather_add (extra blocks) ----
    spmm_csr8<<<SPMM_BLOCKS + GADD_BLOCKS, 256, 0, stream>>>(rowinfo,
                                                             (const unsigned long long*)packed,
                                                             nxt, cur, users, items,
                                                             (float4*)uacc, (float4*)iacc);
    // after this: cur holds layer-2 output, uacc/iacc hold e0 + L1

    // ---- layer 3: batch rows only, with folded layer-2 gather_add ----
    spmm_batch_final8<<<(2 * BATCH) / 4, 256, 0, stream>>>(rowinfo,
                                                           (const unsigned long long*)packed,
                                                           cur, users, items, uacc, iacc);

    // ---- output ----
    dot_out<<<BATCH / 4, 256, 0, stream>>>(uacc, iacc, out);
}